// Round 6
// baseline (91.673 us; speedup 1.0000x reference)
//
#include <hip/hip_runtime.h>
#include <math.h>

// Problem constants (fixed by reference setup_inputs)
constexpr int B   = 128;
constexpr int T   = 300;
constexpr int D   = 1024;   // video dim
constexpr int DA  = 128;    // audio dim
constexpr int TS  = T - 1;  // 299 similarities per batch
constexpr int K   = 32;
constexpr int KP1 = K + 1;

constexpr int NW   = 16;    // waves per block (1024 threads)
constexpr int SEGW = 19;    // sims per wave: 16*19 = 304 >= 299

#define EPS_D 1e-5

__device__ __forceinline__ void loadrow(const float* __restrict__ row, int lane, float r[16]) {
    const float4* f = (const float4*)row;
#pragma unroll
    for (int j = 0; j < 4; ++j) {
        float4 x = f[lane + 64 * j];
        r[4 * j + 0] = x.x; r[4 * j + 1] = x.y;
        r[4 * j + 2] = x.z; r[4 * j + 3] = x.w;
    }
}

// One block per batch. Phase A: adjacent-frame |cosine| sims into LDS
// (f64 accumulation — absmax 0.0 in R0/R1/R4). Phase B: LDS rank-select
// (rank<K are exactly top_k(-sim)'s stable winners; output position = rank).
// Phase C: gather 33 video+audio rows to d_out. Zero global scratch,
// zero extra dispatches.
__global__ __launch_bounds__(1024, 1) void fused1_kernel(const float* __restrict__ video,
                                                         const float* __restrict__ audio,
                                                         float* __restrict__ out) {
    __shared__ float S[TS];
    __shared__ int   idxs[KP1];

    int b    = blockIdx.x;
    int tid  = threadIdx.x;
    int w    = tid >> 6;
    int lane = tid & 63;

    const float* vb = video + (size_t)b * T * D;

    // ---- Phase A: sims for this wave's segment [s0, s0+SEGW) ----
    int s0 = w * SEGW;
    {
        float p[16];
        loadrow(vb + (size_t)s0 * D, lane, p);
        double pn0 = 0.0;
#pragma unroll
        for (int j = 0; j < 16; ++j) pn0 += (double)p[j] * (double)p[j];

        double cnA[SEGW], dtA[SEGW];
#pragma unroll
        for (int i = 0; i < SEGW; ++i) {
            int s = s0 + i;
            int rowIdx = min(s + 1, TS);   // clamp tail loads
            float c[16];
            loadrow(vb + (size_t)rowIdx * D, lane, c);
            double cn = 0.0, dt = 0.0;
#pragma unroll
            for (int j = 0; j < 16; ++j) {
                cn += (double)c[j] * (double)c[j];
                dt += (double)c[j] * (double)p[j];
            }
            cnA[i] = cn; dtA[i] = dt;
#pragma unroll
            for (int j = 0; j < 16; ++j) p[j] = c[j];
        }
#pragma unroll
        for (int o = 32; o; o >>= 1) {
            pn0 += __shfl_xor(pn0, o);
#pragma unroll
            for (int i = 0; i < SEGW; ++i) {
                cnA[i] += __shfl_xor(cnA[i], o);
                dtA[i] += __shfl_xor(dtA[i], o);
            }
        }
        if (lane == 0) {
            double nprev = sqrt(pn0) + EPS_D;
#pragma unroll
            for (int i = 0; i < SEGW; ++i) {
                int s = s0 + i;
                double ncur = sqrt(cnA[i]) + EPS_D;
                if (s < TS) S[s] = (float)(fabs(dtA[i]) / (nprev * ncur));
                nprev = ncur;
            }
        }
    }
    if (tid == 0) idxs[0] = 0;
    __syncthreads();

    // ---- Phase B: rank-select ----
    // rank(e) = #{j : S[j]<S[e] || (S[j]==S[e] && j<e)}; ranks are unique.
    if (tid < TS) {
        float val = S[tid];
        int rank = 0;
#pragma unroll 4
        for (int j = 0; j < TS; ++j) {
            float sj = S[j];
            rank += (sj < val) || (sj == val && j < tid);
        }
        if (rank < K) idxs[rank + 1] = tid + 1;
    }
    __syncthreads();

    // ---- Phase C: gather ----
    // Video: 4×256-thread groups copy 4 rows concurrently (33 rows total).
    int grp  = tid >> 8;     // 0..3
    int l256 = tid & 255;
    for (int k = grp; k < KP1; k += 4) {
        int t = idxs[k];
        const float4* vs = (const float4*)(vb + (size_t)t * D);
        float4*       vd = (float4*)(out + ((size_t)b * KP1 + k) * D);
        vd[l256] = vs[l256];
    }
    // Audio: 33 rows x 32 float4 = 1056 vec4 copies.
    const float* ab   = audio + (size_t)b * T * DA;
    float*       outA = out + (size_t)B * KP1 * D + (size_t)b * KP1 * DA;
    for (int a = tid; a < KP1 * (DA / 4); a += 1024) {
        int k = a >> 5, off = a & 31;
        int t = idxs[k];
        ((float4*)(outA + (size_t)k * DA))[off] =
            ((const float4*)(ab + (size_t)t * DA))[off];
    }
}

extern "C" void kernel_launch(void* const* d_in, const int* in_sizes, int n_in,
                              void* d_out, int out_size, void* d_ws, size_t ws_size,
                              hipStream_t stream) {
    const float* video = (const float*)d_in[0];
    const float* audio = (const float*)d_in[1];
    float* out = (float*)d_out;

    fused1_kernel<<<B, 1024, 0, stream>>>(video, audio, out);
}

// Round 7
// 53.199 us; speedup vs baseline: 1.7232x; 1.7232x over previous
//
#include <hip/hip_runtime.h>
#include <math.h>

// Problem constants (fixed by reference setup_inputs)
constexpr int B   = 128;
constexpr int T   = 300;
constexpr int D   = 1024;   // video dim
constexpr int DA  = 128;    // audio dim
constexpr int TS  = T - 1;  // 299 similarities per batch
constexpr int K   = 32;
constexpr int KP1 = K + 1;

constexpr int SEG  = 8;                       // sims per wave-segment (R1 proven)
constexpr int WPB  = (TS + SEG - 1) / SEG;    // 38 segments per batch
constexpr int NSEG = B * WPB;                 // 4864

#define EPS_D 1e-5

__device__ __forceinline__ void loadrow(const float* __restrict__ row, int lane, float r[16]) {
    const float4* f = (const float4*)row;
#pragma unroll
    for (int j = 0; j < 4; ++j) {
        float4 x = f[lane + 64 * j];
        r[4 * j + 0] = x.x; r[4 * j + 1] = x.y;
        r[4 * j + 2] = x.z; r[4 * j + 3] = x.w;
    }
}

// Kernel 1: adjacent-frame |cosine| similarities — EXACTLY R1's proven body
// (SEG=8 f64 accumulation, batched butterflies; absmax 0.0, no spills at 256thr).
__global__ __launch_bounds__(256) void sims_kernel(const float* __restrict__ video,
                                                   float* __restrict__ sims) {
    int gid  = blockIdx.x * 256 + threadIdx.x;
    int wid  = gid >> 6;
    int lane = threadIdx.x & 63;
    if (wid >= NSEG) return;
    int b   = wid / WPB;
    int seg = wid % WPB;
    int s0  = seg * SEG;
    const float* vb = video + (size_t)b * T * D;

    float p[16];
    loadrow(vb + (size_t)s0 * D, lane, p);
    double pn0 = 0.0;
#pragma unroll
    for (int j = 0; j < 16; ++j) pn0 += (double)p[j] * (double)p[j];

    double cnA[SEG], dtA[SEG];
#pragma unroll
    for (int i = 0; i < SEG; ++i) {
        int s = s0 + i;
        int rowIdx = min(s + 1, TS);   // clamp tail loads
        float c[16];
        loadrow(vb + (size_t)rowIdx * D, lane, c);
        double cn = 0.0, dt = 0.0;
#pragma unroll
        for (int j = 0; j < 16; ++j) {
            cn += (double)c[j] * (double)c[j];
            dt += (double)c[j] * (double)p[j];
        }
        cnA[i] = cn; dtA[i] = dt;
#pragma unroll
        for (int j = 0; j < 16; ++j) p[j] = c[j];
    }

#pragma unroll
    for (int o = 32; o; o >>= 1) {
        pn0 += __shfl_xor(pn0, o);
#pragma unroll
        for (int i = 0; i < SEG; ++i) {
            cnA[i] += __shfl_xor(cnA[i], o);
            dtA[i] += __shfl_xor(dtA[i], o);
        }
    }

    if (lane == 0) {
        double nprev = sqrt(pn0) + EPS_D;
#pragma unroll
        for (int i = 0; i < SEG; ++i) {
            int s = s0 + i;
            double ncur = sqrt(cnA[i]) + EPS_D;
            if (s < TS) sims[b * TS + s] = (float)(fabs(dtA[i]) / (nprev * ncur));
            nprev = ncur;
        }
    }
}

// Kernel 2: fused rank-select + gather, 512 threads/block, one block per batch.
// rank(e) = #{j : S[j]<S[e] || (S[j]==S[e] && j<e)} — rank<K are exactly
// top_k(-sim)'s stable winners; output position = rank. idx stays in LDS.
__global__ __launch_bounds__(512) void selgather_kernel(const float* __restrict__ video,
                                                        const float* __restrict__ audio,
                                                        const float* __restrict__ sims,
                                                        float* __restrict__ out) {
    __shared__ float S[TS];
    __shared__ int   idxs[KP1];
    int b   = blockIdx.x;
    int tid = threadIdx.x;

    if (tid < TS) S[tid] = sims[b * TS + tid];
    if (tid == 0) idxs[0] = 0;
    __syncthreads();

    if (tid < TS) {
        float val = S[tid];
        int rank = 0;
#pragma unroll 4
        for (int j = 0; j < TS; ++j) {
            float sj = S[j];
            rank += (sj < val) || (sj == val && j < tid);
        }
        if (rank < K) idxs[rank + 1] = tid + 1;
    }
    __syncthreads();

    const float* vb = video + (size_t)b * T * D;

    // Video: 2×256-thread groups copy 2 rows concurrently (33 rows, 17 iters).
    int grp  = tid >> 8;     // 0..1
    int l256 = tid & 255;
#pragma unroll 4
    for (int k = grp; k < KP1; k += 2) {
        int t = idxs[k];
        const float4* vs = (const float4*)(vb + (size_t)t * D);
        float4*       vd = (float4*)(out + ((size_t)b * KP1 + k) * D);
        vd[l256] = vs[l256];
    }
    // Audio: 33 rows x 32 float4 = 1056 vec4 copies, strided by 512.
    const float* ab   = audio + (size_t)b * T * DA;
    float*       outA = out + (size_t)B * KP1 * D + (size_t)b * KP1 * DA;
    for (int a = tid; a < KP1 * (DA / 4); a += 512) {
        int k = a >> 5, off = a & 31;
        int t = idxs[k];
        ((float4*)(outA + (size_t)k * DA))[off] =
            ((const float4*)(ab + (size_t)t * DA))[off];
    }
}

extern "C" void kernel_launch(void* const* d_in, const int* in_sizes, int n_in,
                              void* d_out, int out_size, void* d_ws, size_t ws_size,
                              hipStream_t stream) {
    const float* video = (const float*)d_in[0];
    const float* audio = (const float*)d_in[1];
    float* out  = (float*)d_out;
    float* sims = (float*)d_ws;

    int nBlocks = (NSEG * 64 + 255) / 256;   // 1216
    sims_kernel<<<nBlocks, 256, 0, stream>>>(video, sims);
    selgather_kernel<<<B, 512, 0, stream>>>(video, audio, sims, out);
}